// Round 12
// baseline (1557.740 us; speedup 1.0000x reference)
//
#include <hip/hip_runtime.h>
#include <hip/hip_bf16.h>

#define N_TOK 16384
#define H_DIM 2048
#define NE 8
#define CHUNK 2048
#define IPE 1024
#define F2 2048

typedef __bf16 bf16;
typedef bf16 bf16x8 __attribute__((ext_vector_type(8)));
typedef float f32x4 __attribute__((ext_vector_type(4)));

typedef __attribute__((address_space(1))) void gvoid;
typedef __attribute__((address_space(3))) void svoid;

__device__ __forceinline__ void gload_lds16(const void* g, void* l) {
  __builtin_amdgcn_global_load_lds((gvoid*)g, (svoid*)l, 16, 0, 0);
}
__device__ __forceinline__ f32x4 MF(bf16x8 a, bf16x8 b, f32x4 c) {
  return __builtin_amdgcn_mfma_f32_16x16x32_bf16(a, b, c, 0, 0, 0);
}

#define BAR() __builtin_amdgcn_s_barrier()
#define LGKM0() asm volatile("s_waitcnt lgkmcnt(0)" ::: "memory")
#define LGKM8() asm volatile("s_waitcnt lgkmcnt(8)" ::: "memory")
#define VM0() asm volatile("s_waitcnt vmcnt(0)" ::: "memory")
#define PRIO(x) __builtin_amdgcn_s_setprio(x)
#define SCHED0() __builtin_amdgcn_sched_barrier(0)

// ---------------------------------------------------------------------------
// Merged prep (R9 exact — near traffic floor):
//   [0,16384): gather+cvt; [16384,24576): tr_w1 (interleaved); rest: tr_w2
// ---------------------------------------------------------------------------
__global__ __launch_bounds__(256) void k_prep(
    const float* __restrict__ hidden, const int* __restrict__ sidx,
    const float* __restrict__ w1, const float* __restrict__ w2,
    bf16* __restrict__ xs, bf16* __restrict__ w1t, bf16* __restrict__ w2t) {
  int b = blockIdx.x;
  int tid = threadIdx.x;
  if (b < 16384) {
    int row = b;
    int src = sidx[row];
    const float4* ip = (const float4*)(hidden + (size_t)src * H_DIM);
    float4 f0 = ip[tid * 2], f1 = ip[tid * 2 + 1];
    bf16x8 v;
    v[0] = (bf16)f0.x; v[1] = (bf16)f0.y; v[2] = (bf16)f0.z; v[3] = (bf16)f0.w;
    v[4] = (bf16)f1.x; v[5] = (bf16)f1.y; v[6] = (bf16)f1.z; v[7] = (bf16)f1.w;
    *(bf16x8*)(xs + (size_t)row * H_DIM + tid * 8) = v;
    return;
  }
  __shared__ bf16 lds[64][68];
  if (b < 24576) {
    int i1 = b - 16384;
    int fB = i1 & 31, hB = (i1 >> 5) & 31, e = i1 >> 10;
    const float* ip = w1 + ((size_t)e * H_DIM + hB * 64) * F2;
#pragma unroll
    for (int p = 0; p < 4; ++p) {
      int idx = p * 256 + tid;
      int half = idx >> 9, rem = idx & 511;
      int row = rem >> 3, c4 = rem & 7;
      float4 v = *(const float4*)(ip + (size_t)row * F2 + half * 1024 + fB * 32 + c4 * 4);
      bf16* d = &lds[row][half * 32 + c4 * 4];
      d[0] = (bf16)v.x; d[1] = (bf16)v.y; d[2] = (bf16)v.z; d[3] = (bf16)v.w;
    }
    __syncthreads();
    int fl = tid >> 2, hseg = (tid & 3) * 16;
    int g = fl >> 4, w = fl & 15;
    int lcol = ((g >> 1) << 4) + w + ((g & 1) << 5);
    bf16 v[16];
#pragma unroll
    for (int j = 0; j < 16; ++j) v[j] = lds[hseg + j][lcol];
    bf16* op = w1t + ((size_t)e * F2 + fB * 64 + fl) * H_DIM + hB * 64 + hseg;
    *(bf16x8*)op = *(bf16x8*)&v[0];
    *(bf16x8*)(op + 8) = *(bf16x8*)&v[8];
  } else {
    int i2 = b - 24576;
    int hB = i2 & 31, iB = (i2 >> 5) & 15, e = i2 >> 9;
    const float* ip = w2 + (size_t)e * IPE * H_DIM + (size_t)iB * 64 * H_DIM + hB * 64;
#pragma unroll
    for (int p = 0; p < 4; ++p) {
      int idx = p * 256 + tid;
      int row = idx >> 4, c4 = idx & 15;
      float4 v = *(const float4*)(ip + (size_t)row * H_DIM + c4 * 4);
      bf16* d = &lds[row][c4 * 4];
      d[0] = (bf16)v.x; d[1] = (bf16)v.y; d[2] = (bf16)v.z; d[3] = (bf16)v.w;
    }
    __syncthreads();
    int hl = tid >> 2, iseg = (tid & 3) * 16;
    bf16 v[16];
#pragma unroll
    for (int j = 0; j < 16; ++j) v[j] = lds[iseg + j][hl];
    bf16* op = w2t + ((size_t)e * H_DIM + hB * 64 + hl) * IPE + iB * 64 + iseg;
    *(bf16x8*)op = *(bf16x8*)&v[0];
    *(bf16x8*)(op + 8) = *(bf16x8*)&v[8];
  }
}

// ---------------------------------------------------------------------------
// 256x256x64 4-phase grouped GEMM — SINGLE LDS buffer (64 KiB static) ->
// 2 blocks/CU. One variable changed vs R11 (which was dbuf, 1 block/CU,
// MfmaUtil 44%): cross-block wave slip (4 waves/SIMD from 2 independent
// blocks) hides the per-phase barrier/lgkm overhead that a single
// barrier-locked block cannot.
//
// Schedule per K-tile t (R11 quadrant phases, stages consolidated at P3):
//  P0: read A0(8)+B0(4); LGKM8; BAR; LGKM0; MFMA q0; BAR
//  P1: read B1(4);              BAR; LGKM0; MFMA q1; BAR
//  P2: read A1(8, aliased);     BAR; LGKM0; MFMA q2; BAR
//  P3: stage tile t+1 (8 gloads); MFMA q3; VM0; BAR
// Race safety: last reads of the buffer are A1 at P2, drained per-wave by
// P2's post-bar LGKM0 and published by P2's trailing BAR — all before any
// wave issues P3 stages. VM0+BAR at P3 end -> tile t+1 landed for all waves.
// ---------------------------------------------------------------------------
template <int KDIM, bool SILU>
__global__ __launch_bounds__(512, 4) void k_gemm8(
    const bf16* __restrict__ Aptr, const bf16* __restrict__ Bptr,
    const int* __restrict__ sidx, bf16* __restrict__ act,
    float* __restrict__ fout) {
  __shared__ char smem[65536];
  const int tid = threadIdx.x, lane = tid & 63, wv = tid >> 6;
  const int wm = wv >> 2, wn = wv & 3;
  constexpr int NT = KDIM / 64;

  int swzwg = (blockIdx.x & 7) * (gridDim.x >> 3) + (blockIdx.x >> 3);
  const int e = swzwg >> 6, bm = (swzwg >> 3) & 7, bn = swzwg & 7;

  const char* Ab = (const char*)(Aptr + ((size_t)e * CHUNK + bm * 256) * KDIM);
  const char* Bb = (const char*)(Bptr + ((size_t)e * 2048 + bn * 256) * KDIM);

  const int L0 = wv * 1024 + lane * 16;
  const int lin0 = L0 ^ (((L0 >> 7) & 7) << 4);
  const int srow0 = lin0 >> 7, scolb = lin0 & 127;

  const int rA = lane & 15;
  const int swzr = (rA & 7) << 4;
  const int cb = (lane >> 4) * 16;

  // precomputed swizzled fragment-read bases (thread-constant, R11)
  const char* pA0 = smem + wm * 16384 + rA * 128 + ((0 + cb) ^ swzr);
  const char* pA1 = smem + wm * 16384 + rA * 128 + ((64 + cb) ^ swzr);
  const char* pB0 = smem + 32768 + (wn >> 1) * 16384 + (wn & 1) * 8192 +
                    rA * 128 + ((0 + cb) ^ swzr);
  const char* pB1 = smem + 32768 + (wn >> 1) * 16384 + (wn & 1) * 8192 +
                    rA * 128 + ((64 + cb) ^ swzr);

  f32x4 acc[8][4] = {};

  auto stage = [&](int mat, int half, int kt) {
    const char* gb = (mat == 0) ? Ab : Bb;
    char* ld = smem + mat * 32768 + half * 16384 + wv * 1024;
    size_t rb = (size_t)(half * 128 + srow0) * (KDIM * 2) + (size_t)kt * 128 + scolb;
    gload_lds16(gb + rb, ld);
    gload_lds16(gb + rb + (size_t)64 * (KDIM * 2), ld + 8192);
  };

  // prologue: tile 0 staged, landed, published
  stage(1, 0, 0); stage(1, 1, 0); stage(0, 0, 0); stage(0, 1, 0);
  VM0();
  BAR();

  for (int t = 0; t < NT; ++t) {
    bf16x8 AA[4][2], B0[2][2], B1[2][2];
    // ---- P0: read A0(8)+B0(4); MFMA q0 ----
#pragma unroll
    for (int mi = 0; mi < 4; ++mi) {
      AA[mi][0] = *(const bf16x8*)(pA0 + mi * 2048);
      AA[mi][1] = *(const bf16x8*)(pA1 + mi * 2048);
    }
#pragma unroll
    for (int ni = 0; ni < 2; ++ni) {
      B0[ni][0] = *(const bf16x8*)(pB0 + ni * 2048);
      B0[ni][1] = *(const bf16x8*)(pB1 + ni * 2048);
    }
    LGKM8();
    BAR();
    LGKM0();
    SCHED0();
    PRIO(1);
#pragma unroll
    for (int mi = 0; mi < 4; ++mi)
#pragma unroll
      for (int ni = 0; ni < 2; ++ni) {
        acc[mi][ni] = MF(AA[mi][0], B0[ni][0], acc[mi][ni]);
        acc[mi][ni] = MF(AA[mi][1], B0[ni][1], acc[mi][ni]);
      }
    PRIO(0);
    BAR();
    // ---- P1: read B1(4); MFMA q1 ----
#pragma unroll
    for (int ni = 0; ni < 2; ++ni) {
      B1[ni][0] = *(const bf16x8*)(pB0 + (2 + ni) * 2048);
      B1[ni][1] = *(const bf16x8*)(pB1 + (2 + ni) * 2048);
    }
    BAR();
    LGKM0();
    SCHED0();
    PRIO(1);
#pragma unroll
    for (int mi = 0; mi < 4; ++mi)
#pragma unroll
      for (int ni = 0; ni < 2; ++ni) {
        acc[mi][2 + ni] = MF(AA[mi][0], B1[ni][0], acc[mi][2 + ni]);
        acc[mi][2 + ni] = MF(AA[mi][1], B1[ni][1], acc[mi][2 + ni]);
      }
    PRIO(0);
    BAR();
    // ---- P2: read A1(8, aliased); MFMA q2 ----
#pragma unroll
    for (int mi = 0; mi < 4; ++mi) {
      AA[mi][0] = *(const bf16x8*)(pA0 + (4 + mi) * 2048);
      AA[mi][1] = *(const bf16x8*)(pA1 + (4 + mi) * 2048);
    }
    BAR();
    LGKM0();
    SCHED0();
    PRIO(1);
#pragma unroll
    for (int mi = 0; mi < 4; ++mi)
#pragma unroll
      for (int ni = 0; ni < 2; ++ni) {
        acc[4 + mi][ni] = MF(AA[mi][0], B0[ni][0], acc[4 + mi][ni]);
        acc[4 + mi][ni] = MF(AA[mi][1], B0[ni][1], acc[4 + mi][ni]);
      }
    PRIO(0);
    BAR();
    // ---- P3: stage tile t+1; MFMA q3; VM0; BAR ----
    if (t + 1 < NT) {
      stage(1, 0, t + 1); stage(1, 1, t + 1);
      stage(0, 0, t + 1); stage(0, 1, t + 1);
    }
    PRIO(1);
#pragma unroll
    for (int mi = 0; mi < 4; ++mi)
#pragma unroll
      for (int ni = 0; ni < 2; ++ni) {
        acc[4 + mi][2 + ni] = MF(AA[mi][0], B1[ni][0], acc[4 + mi][2 + ni]);
        acc[4 + mi][2 + ni] = MF(AA[mi][1], B1[ni][1], acc[4 + mi][2 + ni]);
      }
    PRIO(0);
    if (t + 1 < NT) VM0();
    BAR();
  }

  if constexpr (SILU) {
    bf16* actp = act + ((size_t)e * CHUNK + bm * 256 + wm * 128) * IPE;
    const int r0 = (lane >> 4) * 4;
    const int c0 = bn * 128 + wn * 32 + (lane & 15);
#pragma unroll
    for (int mi = 0; mi < 8; ++mi)
#pragma unroll
      for (int p = 0; p < 2; ++p) {
        f32x4 g = acc[mi][2 * p], u = acc[mi][2 * p + 1];
#pragma unroll
        for (int r = 0; r < 4; ++r) {
          float gv = g[r];
          float a = gv / (1.f + __expf(-gv)) * u[r];
          actp[(size_t)(mi * 16 + r0 + r) * IPE + c0 + p * 16] = (bf16)a;
        }
      }
  } else {
    const int* sp = sidx + e * CHUNK + bm * 256 + wm * 128;
    const int r0 = (lane >> 4) * 4;
    const int c0 = bn * 256 + wn * 64 + (lane & 15);
#pragma unroll
    for (int mi = 0; mi < 8; ++mi)
#pragma unroll
      for (int r = 0; r < 4; ++r) {
        int dst = sp[mi * 16 + r0 + r];
        float* op = fout + (size_t)dst * H_DIM + c0;
#pragma unroll
        for (int ni = 0; ni < 4; ++ni) op[ni * 16] = acc[mi][ni][r];
      }
  }
}

// ---------------------------------------------------------------------------
extern "C" void kernel_launch(void* const* d_in, const int* in_sizes, int n_in,
                              void* d_out, int out_size, void* d_ws, size_t ws_size,
                              hipStream_t stream) {
  const float* hidden = (const float*)d_in[0];
  const int* sidx = (const int*)d_in[1];
  const float* w1 = (const float*)d_in[2];
  const float* w2 = (const float*)d_in[3];
  float* out = (float*)d_out;

  // Workspace (192 MiB): xs [0,64M), w1t [64,128M), w2t [128,160M), act [160,192M)
  char* ws = (char*)d_ws;
  bf16* xs  = (bf16*)(ws);
  bf16* w1t = (bf16*)(ws + (size_t)67108864);
  bf16* w2t = (bf16*)(ws + (size_t)134217728);
  bf16* act = (bf16*)(ws + (size_t)167772160);

  k_prep<<<dim3(28672), 256, 0, stream>>>(hidden, sidx, w1, w2, xs, w1t, w2t);
  k_gemm8<H_DIM, true><<<dim3(512), 512, 0, stream>>>(xs, w1t, nullptr, act, nullptr);
  k_gemm8<IPE, false><<<dim3(512), 512, 0, stream>>>(act, w2t, sidx, nullptr, out);
}

// Round 13
// 303.619 us; speedup vs baseline: 5.1306x; 5.1306x over previous
//
#include <hip/hip_runtime.h>
#include <hip/hip_bf16.h>

#define N_TOK 16384
#define H_DIM 2048
#define NE 8
#define CHUNK 2048
#define IPE 1024
#define F2 2048

typedef __bf16 bf16;
typedef bf16 bf16x8 __attribute__((ext_vector_type(8)));
typedef float f32x4 __attribute__((ext_vector_type(4)));

typedef __attribute__((address_space(1))) void gvoid;
typedef __attribute__((address_space(3))) void svoid;

__device__ __forceinline__ void gload_lds16(const void* g, void* l) {
  __builtin_amdgcn_global_load_lds((gvoid*)g, (svoid*)l, 16, 0, 0);
}
__device__ __forceinline__ f32x4 MF(bf16x8 a, bf16x8 b, f32x4 c) {
  return __builtin_amdgcn_mfma_f32_16x16x32_bf16(a, b, c, 0, 0, 0);
}

#define BAR() __builtin_amdgcn_s_barrier()
#define LGKM0() asm volatile("s_waitcnt lgkmcnt(0)" ::: "memory")
#define LGKM8() asm volatile("s_waitcnt lgkmcnt(8)" ::: "memory")
#define VM6() asm volatile("s_waitcnt vmcnt(6)" ::: "memory")
#define VM0() asm volatile("s_waitcnt vmcnt(0)" ::: "memory")
#define PRIO(x) __builtin_amdgcn_s_setprio(x)
#define SCHED0() __builtin_amdgcn_sched_barrier(0)

// ---------------------------------------------------------------------------
// Prep launch 1: gather+cvt (blocks [0,16384)) + tr_w1 (blocks [16384,24576)).
// w2 transpose moved into the GEMM1 launch (heterogeneous grid) — it has no
// dependency on GEMM1 and rides its idle HBM bandwidth.
// ---------------------------------------------------------------------------
__global__ __launch_bounds__(256) void k_prep(
    const float* __restrict__ hidden, const int* __restrict__ sidx,
    const float* __restrict__ w1,
    bf16* __restrict__ xs, bf16* __restrict__ w1t) {
  int b = blockIdx.x;
  int tid = threadIdx.x;
  if (b < 16384) {
    int row = b;
    int src = sidx[row];
    const float4* ip = (const float4*)(hidden + (size_t)src * H_DIM);
    float4 f0 = ip[tid * 2], f1 = ip[tid * 2 + 1];
    bf16x8 v;
    v[0] = (bf16)f0.x; v[1] = (bf16)f0.y; v[2] = (bf16)f0.z; v[3] = (bf16)f0.w;
    v[4] = (bf16)f1.x; v[5] = (bf16)f1.y; v[6] = (bf16)f1.z; v[7] = (bf16)f1.w;
    *(bf16x8*)(xs + (size_t)row * H_DIM + tid * 8) = v;
    return;
  }
  __shared__ bf16 lds[64][68];
  int i1 = b - 16384;
  int fB = i1 & 31, hB = (i1 >> 5) & 31, e = i1 >> 10;
  const float* ip = w1 + ((size_t)e * H_DIM + hB * 64) * F2;
#pragma unroll
  for (int p = 0; p < 4; ++p) {
    int idx = p * 256 + tid;
    int half = idx >> 9, rem = idx & 511;
    int row = rem >> 3, c4 = rem & 7;
    float4 v = *(const float4*)(ip + (size_t)row * F2 + half * 1024 + fB * 32 + c4 * 4);
    bf16* d = &lds[row][half * 32 + c4 * 4];
    d[0] = (bf16)v.x; d[1] = (bf16)v.y; d[2] = (bf16)v.z; d[3] = (bf16)v.w;
  }
  __syncthreads();
  int fl = tid >> 2, hseg = (tid & 3) * 16;
  int g = fl >> 4, w = fl & 15;
  int lcol = ((g >> 1) << 4) + w + ((g & 1) << 5);
  bf16 v[16];
#pragma unroll
  for (int j = 0; j < 16; ++j) v[j] = lds[hseg + j][lcol];
  bf16* op = w1t + ((size_t)e * F2 + fB * 64 + fl) * H_DIM + hB * 64 + hseg;
  *(bf16x8*)op = *(bf16x8*)&v[0];
  *(bf16x8*)(op + 8) = *(bf16x8*)&v[8];
}

// ---------------------------------------------------------------------------
// 256x256x64 8-phase grouped GEMM (R11 exact: precomputed swizzled LDS base
// pointers, quadrant phases, counted vmcnt(6), dbuf 128 KiB).
// SILU instantiation additionally carries 2048 w2-transpose blocks
// (blockIdx >= 512): each does two 64x64 fp32->bf16 transposes in the first
// 17 KB of dynamic smem. Dispatched after the GEMM blocks, they fill CU
// gaps and hide their ~100 MB under GEMM1's idle BW. Stream order still
// guarantees w2t is complete before the GEMM2 launch.
// ---------------------------------------------------------------------------
template <int KDIM, bool SILU>
__global__ __launch_bounds__(512, 2) void k_gemm8(
    const bf16* __restrict__ Aptr, const bf16* __restrict__ Bptr,
    const int* __restrict__ sidx, bf16* __restrict__ act,
    float* __restrict__ fout, const float* __restrict__ w2src,
    bf16* __restrict__ w2t) {
  extern __shared__ char smem[];
  const int tid = threadIdx.x;

  if constexpr (SILU) {
    if (blockIdx.x >= 512) {
      // ---- w2 transpose side-blocks: 2048 blocks x 2 tiles of 64x64 ----
      bf16(*lds)[68] = (bf16(*)[68])smem;
#pragma unroll
      for (int q = 0; q < 2; ++q) {
        int tile = (blockIdx.x - 512) * 2 + q;  // 4096 tiles: hB(32) iB(16) e(8)
        int hB = tile & 31, iB = (tile >> 5) & 15, e = tile >> 9;
        const float* ip = w2src + (size_t)e * IPE * H_DIM +
                          (size_t)iB * 64 * H_DIM + hB * 64;
#pragma unroll
        for (int p = 0; p < 2; ++p) {
          int idx = p * 512 + tid;
          int row = idx >> 4, c4 = idx & 15;
          float4 v = *(const float4*)(ip + (size_t)row * H_DIM + c4 * 4);
          bf16* d = &lds[row][c4 * 4];
          d[0] = (bf16)v.x; d[1] = (bf16)v.y; d[2] = (bf16)v.z; d[3] = (bf16)v.w;
        }
        __syncthreads();
        int hl = tid >> 3, iseg = (tid & 7) * 8;
        bf16 v[8];
#pragma unroll
        for (int j = 0; j < 8; ++j) v[j] = lds[iseg + j][hl];
        bf16* op = w2t + ((size_t)e * H_DIM + hB * 64 + hl) * IPE + iB * 64 + iseg;
        *(bf16x8*)op = *(bf16x8*)&v[0];
        __syncthreads();
      }
      return;
    }
  }

  const int lane = tid & 63, wv = tid >> 6;
  const int wm = wv >> 2, wn = wv & 3;
  constexpr int NT = KDIM / 64;

  // XCD swizzle over the 512 GEMM blocks (512/8 = 64 per XCD, bijective)
  int swzwg = (blockIdx.x & 7) * 64 + (blockIdx.x >> 3);
  const int e = swzwg >> 6, bm = (swzwg >> 3) & 7, bn = swzwg & 7;

  const char* Ab = (const char*)(Aptr + ((size_t)e * CHUNK + bm * 256) * KDIM);
  const char* Bb = (const char*)(Bptr + ((size_t)e * 2048 + bn * 256) * KDIM);

  const int L0 = wv * 1024 + lane * 16;
  const int lin0 = L0 ^ (((L0 >> 7) & 7) << 4);
  const int srow0 = lin0 >> 7, scolb = lin0 & 127;

  const int rA = lane & 15;
  const int swzr = (rA & 7) << 4;
  const int cb = (lane >> 4) * 16;

  // precomputed swizzled fragment-read bases (thread-constant, R11)
  const char* pA0 = smem + wm * 16384 + rA * 128 + ((0 + cb) ^ swzr);
  const char* pA1 = smem + wm * 16384 + rA * 128 + ((64 + cb) ^ swzr);
  const char* pB0 = smem + 32768 + (wn >> 1) * 16384 + (wn & 1) * 8192 +
                    rA * 128 + ((0 + cb) ^ swzr);
  const char* pB1 = smem + 32768 + (wn >> 1) * 16384 + (wn & 1) * 8192 +
                    rA * 128 + ((64 + cb) ^ swzr);

  f32x4 acc[8][4] = {};

  auto stage = [&](int buf, int mat, int half, int kt) {
    const char* gb = (mat == 0) ? Ab : Bb;
    char* ld = smem + buf * 65536 + mat * 32768 + half * 16384 + wv * 1024;
    size_t rb = (size_t)(half * 128 + srow0) * (KDIM * 2) + (size_t)kt * 128 + scolb;
    gload_lds16(gb + rb, ld);
    gload_lds16(gb + rb + (size_t)64 * (KDIM * 2), ld + 8192);
  };

  stage(0, 1, 0, 0); stage(0, 1, 1, 0); stage(0, 0, 0, 0); stage(0, 0, 1, 0);
  stage(1, 1, 0, 1); stage(1, 1, 1, 1); stage(1, 0, 0, 1);
  VM6();
  BAR();

  auto ktile = [&](int t, int cur) {
    const int nxt = cur ^ 1;
    const int bo = cur * 65536;
    const char* a0 = pA0 + bo;
    const char* a1 = pA1 + bo;
    const char* b0p = pB0 + bo;
    const char* b1p = pB1 + bo;
    bf16x8 AA[4][2], B0[2][2], B1[2][2];
    // ---- P0: read A0(8)+B0(4); stage t+1.A1; MFMA mi0-3 x ni0-1 ----
#pragma unroll
    for (int mi = 0; mi < 4; ++mi) {
      AA[mi][0] = *(const bf16x8*)(a0 + mi * 2048);
      AA[mi][1] = *(const bf16x8*)(a1 + mi * 2048);
    }
#pragma unroll
    for (int ni = 0; ni < 2; ++ni) {
      B0[ni][0] = *(const bf16x8*)(b0p + ni * 2048);
      B0[ni][1] = *(const bf16x8*)(b1p + ni * 2048);
    }
    if (t + 1 < NT) stage(nxt, 0, 1, t + 1);
    LGKM8();
    BAR();
    LGKM0();
    SCHED0();
    PRIO(1);
#pragma unroll
    for (int mi = 0; mi < 4; ++mi)
#pragma unroll
      for (int ni = 0; ni < 2; ++ni) {
        acc[mi][ni] = MF(AA[mi][0], B0[ni][0], acc[mi][ni]);
        acc[mi][ni] = MF(AA[mi][1], B0[ni][1], acc[mi][ni]);
      }
    PRIO(0);
    BAR();
    // ---- P1: read B1(4); stage t+2.B0; MFMA mi0-3 x ni2-3 ----
#pragma unroll
    for (int ni = 0; ni < 2; ++ni) {
      B1[ni][0] = *(const bf16x8*)(b0p + (2 + ni) * 2048);
      B1[ni][1] = *(const bf16x8*)(b1p + (2 + ni) * 2048);
    }
    if (t + 2 < NT) stage(cur, 1, 0, t + 2);
    BAR();
    LGKM0();
    SCHED0();
    PRIO(1);
#pragma unroll
    for (int mi = 0; mi < 4; ++mi)
#pragma unroll
      for (int ni = 0; ni < 2; ++ni) {
        acc[mi][2 + ni] = MF(AA[mi][0], B1[ni][0], acc[mi][2 + ni]);
        acc[mi][2 + ni] = MF(AA[mi][1], B1[ni][1], acc[mi][2 + ni]);
      }
    PRIO(0);
    BAR();
    // ---- P2: read A1(8) (aliased); stage t+2.B1; MFMA mi4-7 x ni0-1 ----
#pragma unroll
    for (int mi = 0; mi < 4; ++mi) {
      AA[mi][0] = *(const bf16x8*)(a0 + (4 + mi) * 2048);
      AA[mi][1] = *(const bf16x8*)(a1 + (4 + mi) * 2048);
    }
    if (t + 2 < NT) stage(cur, 1, 1, t + 2);
    BAR();
    LGKM0();
    SCHED0();
    PRIO(1);
#pragma unroll
    for (int mi = 0; mi < 4; ++mi)
#pragma unroll
      for (int ni = 0; ni < 2; ++ni) {
        acc[4 + mi][ni] = MF(AA[mi][0], B0[ni][0], acc[4 + mi][ni]);
        acc[4 + mi][ni] = MF(AA[mi][1], B0[ni][1], acc[4 + mi][ni]);
      }
    PRIO(0);
    BAR();
    // ---- P3: stage t+2.A0 + vmcnt(6); MFMA mi4-7 x ni2-3 ----
    if (t + 2 < NT) {
      stage(cur, 0, 0, t + 2);
      VM6();
    } else if (t + 1 < NT) {
      VM0();
    }
    BAR();
    PRIO(1);
#pragma unroll
    for (int mi = 0; mi < 4; ++mi)
#pragma unroll
      for (int ni = 0; ni < 2; ++ni) {
        acc[4 + mi][2 + ni] = MF(AA[mi][0], B1[ni][0], acc[4 + mi][2 + ni]);
        acc[4 + mi][2 + ni] = MF(AA[mi][1], B1[ni][1], acc[4 + mi][2 + ni]);
      }
    PRIO(0);
    BAR();
  };

  for (int tt = 0; tt < NT; tt += 2) {
    ktile(tt, 0);
    ktile(tt + 1, 1);
  }

  if constexpr (SILU) {
    bf16* actp = act + ((size_t)e * CHUNK + bm * 256 + wm * 128) * IPE;
    const int r0 = (lane >> 4) * 4;
    const int c0 = bn * 128 + wn * 32 + (lane & 15);
#pragma unroll
    for (int mi = 0; mi < 8; ++mi)
#pragma unroll
      for (int p = 0; p < 2; ++p) {
        f32x4 g = acc[mi][2 * p], u = acc[mi][2 * p + 1];
#pragma unroll
        for (int r = 0; r < 4; ++r) {
          float gv = g[r];
          float a = gv / (1.f + __expf(-gv)) * u[r];
          actp[(size_t)(mi * 16 + r0 + r) * IPE + c0 + p * 16] = (bf16)a;
        }
      }
  } else {
    const int* sp = sidx + e * CHUNK + bm * 256 + wm * 128;
    const int r0 = (lane >> 4) * 4;
    const int c0 = bn * 256 + wn * 64 + (lane & 15);
#pragma unroll
    for (int mi = 0; mi < 8; ++mi)
#pragma unroll
      for (int r = 0; r < 4; ++r) {
        int dst = sp[mi * 16 + r0 + r];
        float* op = fout + (size_t)dst * H_DIM + c0;
#pragma unroll
        for (int ni = 0; ni < 4; ++ni) op[ni * 16] = acc[mi][ni][r];
      }
  }
}

// ---------------------------------------------------------------------------
extern "C" void kernel_launch(void* const* d_in, const int* in_sizes, int n_in,
                              void* d_out, int out_size, void* d_ws, size_t ws_size,
                              hipStream_t stream) {
  const float* hidden = (const float*)d_in[0];
  const int* sidx = (const int*)d_in[1];
  const float* w1 = (const float*)d_in[2];
  const float* w2 = (const float*)d_in[3];
  float* out = (float*)d_out;

  // Workspace (192 MiB): xs [0,64M), w1t [64,128M), w2t [128,160M), act [160,192M)
  char* ws = (char*)d_ws;
  bf16* xs  = (bf16*)(ws);
  bf16* w1t = (bf16*)(ws + (size_t)67108864);
  bf16* w2t = (bf16*)(ws + (size_t)134217728);
  bf16* act = (bf16*)(ws + (size_t)167772160);

  hipFuncSetAttribute((const void*)k_gemm8<H_DIM, true>,
                      hipFuncAttributeMaxDynamicSharedMemorySize, 131072);
  hipFuncSetAttribute((const void*)k_gemm8<IPE, false>,
                      hipFuncAttributeMaxDynamicSharedMemorySize, 131072);

  k_prep<<<dim3(24576), 256, 0, stream>>>(hidden, sidx, w1, xs, w1t);
  // GEMM1 (blocks 0-511) + w2 transpose side-blocks (512-2559)
  k_gemm8<H_DIM, true><<<dim3(2560), 512, 131072, stream>>>(
      xs, w1t, nullptr, act, nullptr, w2, w2t);
  k_gemm8<IPE, false><<<dim3(512), 512, 131072, stream>>>(
      act, w2t, sidx, nullptr, out, nullptr, nullptr);
}

// Round 14
// 296.889 us; speedup vs baseline: 5.2469x; 1.0227x over previous
//
#include <hip/hip_runtime.h>
#include <hip/hip_bf16.h>

#define N_TOK 16384
#define H_DIM 2048
#define NE 8
#define CHUNK 2048
#define IPE 1024
#define F2 2048

typedef __bf16 bf16;
typedef bf16 bf16x8 __attribute__((ext_vector_type(8)));
typedef float f32x4 __attribute__((ext_vector_type(4)));

typedef __attribute__((address_space(1))) void gvoid;
typedef __attribute__((address_space(3))) void svoid;

__device__ __forceinline__ void gload_lds16(const void* g, void* l) {
  __builtin_amdgcn_global_load_lds((gvoid*)g, (svoid*)l, 16, 0, 0);
}
__device__ __forceinline__ f32x4 MF(bf16x8 a, bf16x8 b, f32x4 c) {
  return __builtin_amdgcn_mfma_f32_16x16x32_bf16(a, b, c, 0, 0, 0);
}

#define BAR() __builtin_amdgcn_s_barrier()
#define LGKM0() asm volatile("s_waitcnt lgkmcnt(0)" ::: "memory")
#define LGKM8() asm volatile("s_waitcnt lgkmcnt(8)" ::: "memory")
#define VM6() asm volatile("s_waitcnt vmcnt(6)" ::: "memory")
#define VM0() asm volatile("s_waitcnt vmcnt(0)" ::: "memory")
#define PRIO(x) __builtin_amdgcn_s_setprio(x)
#define SCHED0() __builtin_amdgcn_sched_barrier(0)

// ---------------------------------------------------------------------------
// Merged prep (R9/R11 structure). LDS padding fixed: [64][70] -> row stride
// 35 dwords (ODD), so store-phase column reads (hseg ∈ {0,16,32,48}) land on
// distinct banks (was: stride 34 -> 2*hseg ≡ 0 mod 32 -> 4-way) and
// write-phase 8B stores are ≤2-way (free, m136).
//   [0,16384): gather+cvt; [16384,24576): tr_w1 (interleaved); rest: tr_w2
// ---------------------------------------------------------------------------
__global__ __launch_bounds__(256) void k_prep(
    const float* __restrict__ hidden, const int* __restrict__ sidx,
    const float* __restrict__ w1, const float* __restrict__ w2,
    bf16* __restrict__ xs, bf16* __restrict__ w1t, bf16* __restrict__ w2t) {
  int b = blockIdx.x;
  int tid = threadIdx.x;
  if (b < 16384) {
    int row = b;
    int src = sidx[row];
    const float4* ip = (const float4*)(hidden + (size_t)src * H_DIM);
    float4 f0 = ip[tid * 2], f1 = ip[tid * 2 + 1];
    bf16x8 v;
    v[0] = (bf16)f0.x; v[1] = (bf16)f0.y; v[2] = (bf16)f0.z; v[3] = (bf16)f0.w;
    v[4] = (bf16)f1.x; v[5] = (bf16)f1.y; v[6] = (bf16)f1.z; v[7] = (bf16)f1.w;
    *(bf16x8*)(xs + (size_t)row * H_DIM + tid * 8) = v;
    return;
  }
  __shared__ bf16 lds[64][70];
  if (b < 24576) {
    int i1 = b - 16384;
    int fB = i1 & 31, hB = (i1 >> 5) & 31, e = i1 >> 10;
    const float* ip = w1 + ((size_t)e * H_DIM + hB * 64) * F2;
#pragma unroll
    for (int p = 0; p < 4; ++p) {
      int idx = p * 256 + tid;
      int half = idx >> 9, rem = idx & 511;
      int row = rem >> 3, c4 = rem & 7;
      float4 v = *(const float4*)(ip + (size_t)row * F2 + half * 1024 + fB * 32 + c4 * 4);
      bf16* d = &lds[row][half * 32 + c4 * 4];
      d[0] = (bf16)v.x; d[1] = (bf16)v.y; d[2] = (bf16)v.z; d[3] = (bf16)v.w;
    }
    __syncthreads();
    int fl = tid >> 2, hseg = (tid & 3) * 16;
    int g = fl >> 4, w = fl & 15;
    int lcol = ((g >> 1) << 4) + w + ((g & 1) << 5);
    bf16 v[16];
#pragma unroll
    for (int j = 0; j < 16; ++j) v[j] = lds[hseg + j][lcol];
    bf16* op = w1t + ((size_t)e * F2 + fB * 64 + fl) * H_DIM + hB * 64 + hseg;
    *(bf16x8*)op = *(bf16x8*)&v[0];
    *(bf16x8*)(op + 8) = *(bf16x8*)&v[8];
  } else {
    int i2 = b - 24576;
    int hB = i2 & 31, iB = (i2 >> 5) & 15, e = i2 >> 9;
    const float* ip = w2 + (size_t)e * IPE * H_DIM + (size_t)iB * 64 * H_DIM + hB * 64;
#pragma unroll
    for (int p = 0; p < 4; ++p) {
      int idx = p * 256 + tid;
      int row = idx >> 4, c4 = idx & 15;
      float4 v = *(const float4*)(ip + (size_t)row * H_DIM + c4 * 4);
      bf16* d = &lds[row][c4 * 4];
      d[0] = (bf16)v.x; d[1] = (bf16)v.y; d[2] = (bf16)v.z; d[3] = (bf16)v.w;
    }
    __syncthreads();
    int hl = tid >> 2, iseg = (tid & 3) * 16;
    bf16 v[16];
#pragma unroll
    for (int j = 0; j < 16; ++j) v[j] = lds[iseg + j][hl];
    bf16* op = w2t + ((size_t)e * H_DIM + hB * 64 + hl) * IPE + iB * 64 + iseg;
    *(bf16x8*)op = *(bf16x8*)&v[0];
    *(bf16x8*)(op + 8) = *(bf16x8*)&v[8];
  }
}

// ---------------------------------------------------------------------------
// 256x256x64 8-phase grouped GEMM (R11 exact — proven 135.7/66 us):
// precomputed swizzled LDS base pointers, quadrant phases, counted vmcnt(6),
// dbuf 128 KiB, XCD swizzle.
// ---------------------------------------------------------------------------
template <int KDIM, bool SILU>
__global__ __launch_bounds__(512, 2) void k_gemm8(
    const bf16* __restrict__ Aptr, const bf16* __restrict__ Bptr,
    const int* __restrict__ sidx, bf16* __restrict__ act,
    float* __restrict__ fout) {
  extern __shared__ char smem[];
  const int tid = threadIdx.x, lane = tid & 63, wv = tid >> 6;
  const int wm = wv >> 2, wn = wv & 3;
  constexpr int NT = KDIM / 64;

  int swzwg = (blockIdx.x & 7) * (gridDim.x >> 3) + (blockIdx.x >> 3);
  const int e = swzwg >> 6, bm = (swzwg >> 3) & 7, bn = swzwg & 7;

  const char* Ab = (const char*)(Aptr + ((size_t)e * CHUNK + bm * 256) * KDIM);
  const char* Bb = (const char*)(Bptr + ((size_t)e * 2048 + bn * 256) * KDIM);

  const int L0 = wv * 1024 + lane * 16;
  const int lin0 = L0 ^ (((L0 >> 7) & 7) << 4);
  const int srow0 = lin0 >> 7, scolb = lin0 & 127;

  const int rA = lane & 15;
  const int swzr = (rA & 7) << 4;
  const int cb = (lane >> 4) * 16;

  // precomputed swizzled fragment-read bases (thread-constant)
  const char* pA0 = smem + wm * 16384 + rA * 128 + ((0 + cb) ^ swzr);
  const char* pA1 = smem + wm * 16384 + rA * 128 + ((64 + cb) ^ swzr);
  const char* pB0 = smem + 32768 + (wn >> 1) * 16384 + (wn & 1) * 8192 +
                    rA * 128 + ((0 + cb) ^ swzr);
  const char* pB1 = smem + 32768 + (wn >> 1) * 16384 + (wn & 1) * 8192 +
                    rA * 128 + ((64 + cb) ^ swzr);

  f32x4 acc[8][4] = {};

  auto stage = [&](int buf, int mat, int half, int kt) {
    const char* gb = (mat == 0) ? Ab : Bb;
    char* ld = smem + buf * 65536 + mat * 32768 + half * 16384 + wv * 1024;
    size_t rb = (size_t)(half * 128 + srow0) * (KDIM * 2) + (size_t)kt * 128 + scolb;
    gload_lds16(gb + rb, ld);
    gload_lds16(gb + rb + (size_t)64 * (KDIM * 2), ld + 8192);
  };

  stage(0, 1, 0, 0); stage(0, 1, 1, 0); stage(0, 0, 0, 0); stage(0, 0, 1, 0);
  stage(1, 1, 0, 1); stage(1, 1, 1, 1); stage(1, 0, 0, 1);
  VM6();
  BAR();

  auto ktile = [&](int t, int cur) {
    const int nxt = cur ^ 1;
    const int bo = cur * 65536;
    const char* a0 = pA0 + bo;
    const char* a1 = pA1 + bo;
    const char* b0p = pB0 + bo;
    const char* b1p = pB1 + bo;
    bf16x8 AA[4][2], B0[2][2], B1[2][2];
    // ---- P0: read A0(8)+B0(4); stage t+1.A1; MFMA mi0-3 x ni0-1 ----
#pragma unroll
    for (int mi = 0; mi < 4; ++mi) {
      AA[mi][0] = *(const bf16x8*)(a0 + mi * 2048);
      AA[mi][1] = *(const bf16x8*)(a1 + mi * 2048);
    }
#pragma unroll
    for (int ni = 0; ni < 2; ++ni) {
      B0[ni][0] = *(const bf16x8*)(b0p + ni * 2048);
      B0[ni][1] = *(const bf16x8*)(b1p + ni * 2048);
    }
    if (t + 1 < NT) stage(nxt, 0, 1, t + 1);
    LGKM8();
    BAR();
    LGKM0();
    SCHED0();
    PRIO(1);
#pragma unroll
    for (int mi = 0; mi < 4; ++mi)
#pragma unroll
      for (int ni = 0; ni < 2; ++ni) {
        acc[mi][ni] = MF(AA[mi][0], B0[ni][0], acc[mi][ni]);
        acc[mi][ni] = MF(AA[mi][1], B0[ni][1], acc[mi][ni]);
      }
    PRIO(0);
    BAR();
    // ---- P1: read B1(4); stage t+2.B0; MFMA mi0-3 x ni2-3 ----
#pragma unroll
    for (int ni = 0; ni < 2; ++ni) {
      B1[ni][0] = *(const bf16x8*)(b0p + (2 + ni) * 2048);
      B1[ni][1] = *(const bf16x8*)(b1p + (2 + ni) * 2048);
    }
    if (t + 2 < NT) stage(cur, 1, 0, t + 2);
    BAR();
    LGKM0();
    SCHED0();
    PRIO(1);
#pragma unroll
    for (int mi = 0; mi < 4; ++mi)
#pragma unroll
      for (int ni = 0; ni < 2; ++ni) {
        acc[mi][2 + ni] = MF(AA[mi][0], B1[ni][0], acc[mi][2 + ni]);
        acc[mi][2 + ni] = MF(AA[mi][1], B1[ni][1], acc[mi][2 + ni]);
      }
    PRIO(0);
    BAR();
    // ---- P2: read A1(8) (aliased); stage t+2.B1; MFMA mi4-7 x ni0-1 ----
#pragma unroll
    for (int mi = 0; mi < 4; ++mi) {
      AA[mi][0] = *(const bf16x8*)(a0 + (4 + mi) * 2048);
      AA[mi][1] = *(const bf16x8*)(a1 + (4 + mi) * 2048);
    }
    if (t + 2 < NT) stage(cur, 1, 1, t + 2);
    BAR();
    LGKM0();
    SCHED0();
    PRIO(1);
#pragma unroll
    for (int mi = 0; mi < 4; ++mi)
#pragma unroll
      for (int ni = 0; ni < 2; ++ni) {
        acc[4 + mi][ni] = MF(AA[mi][0], B0[ni][0], acc[4 + mi][ni]);
        acc[4 + mi][ni] = MF(AA[mi][1], B0[ni][1], acc[4 + mi][ni]);
      }
    PRIO(0);
    BAR();
    // ---- P3: stage t+2.A0 + vmcnt(6); MFMA mi4-7 x ni2-3 ----
    if (t + 2 < NT) {
      stage(cur, 0, 0, t + 2);
      VM6();
    } else if (t + 1 < NT) {
      VM0();
    }
    BAR();
    PRIO(1);
#pragma unroll
    for (int mi = 0; mi < 4; ++mi)
#pragma unroll
      for (int ni = 0; ni < 2; ++ni) {
        acc[4 + mi][2 + ni] = MF(AA[mi][0], B1[ni][0], acc[4 + mi][2 + ni]);
        acc[4 + mi][2 + ni] = MF(AA[mi][1], B1[ni][1], acc[4 + mi][2 + ni]);
      }
    PRIO(0);
    BAR();
  };

  for (int tt = 0; tt < NT; tt += 2) {
    ktile(tt, 0);
    ktile(tt + 1, 1);
  }

  if constexpr (SILU) {
    bf16* actp = act + ((size_t)e * CHUNK + bm * 256 + wm * 128) * IPE;
    const int r0 = (lane >> 4) * 4;
    const int c0 = bn * 128 + wn * 32 + (lane & 15);
#pragma unroll
    for (int mi = 0; mi < 8; ++mi)
#pragma unroll
      for (int p = 0; p < 2; ++p) {
        f32x4 g = acc[mi][2 * p], u = acc[mi][2 * p + 1];
#pragma unroll
        for (int r = 0; r < 4; ++r) {
          float gv = g[r];
          float a = gv / (1.f + __expf(-gv)) * u[r];
          actp[(size_t)(mi * 16 + r0 + r) * IPE + c0 + p * 16] = (bf16)a;
        }
      }
  } else {
    const int* sp = sidx + e * CHUNK + bm * 256 + wm * 128;
    const int r0 = (lane >> 4) * 4;
    const int c0 = bn * 256 + wn * 64 + (lane & 15);
#pragma unroll
    for (int mi = 0; mi < 8; ++mi)
#pragma unroll
      for (int r = 0; r < 4; ++r) {
        int dst = sp[mi * 16 + r0 + r];
        float* op = fout + (size_t)dst * H_DIM + c0;
#pragma unroll
        for (int ni = 0; ni < 4; ++ni) op[ni * 16] = acc[mi][ni][r];
      }
  }
}

// ---------------------------------------------------------------------------
extern "C" void kernel_launch(void* const* d_in, const int* in_sizes, int n_in,
                              void* d_out, int out_size, void* d_ws, size_t ws_size,
                              hipStream_t stream) {
  const float* hidden = (const float*)d_in[0];
  const int* sidx = (const int*)d_in[1];
  const float* w1 = (const float*)d_in[2];
  const float* w2 = (const float*)d_in[3];
  float* out = (float*)d_out;

  // Workspace (192 MiB): xs [0,64M), w1t [64,128M), w2t [128,160M), act [160,192M)
  char* ws = (char*)d_ws;
  bf16* xs  = (bf16*)(ws);
  bf16* w1t = (bf16*)(ws + (size_t)67108864);
  bf16* w2t = (bf16*)(ws + (size_t)134217728);
  bf16* act = (bf16*)(ws + (size_t)167772160);

  hipFuncSetAttribute((const void*)k_gemm8<H_DIM, true>,
                      hipFuncAttributeMaxDynamicSharedMemorySize, 131072);
  hipFuncSetAttribute((const void*)k_gemm8<IPE, false>,
                      hipFuncAttributeMaxDynamicSharedMemorySize, 131072);

  k_prep<<<dim3(28672), 256, 0, stream>>>(hidden, sidx, w1, w2, xs, w1t, w2t);
  k_gemm8<H_DIM, true><<<dim3(512), 512, 131072, stream>>>(xs, w1t, nullptr, act, nullptr);
  k_gemm8<IPE, false><<<dim3(512), 512, 131072, stream>>>(act, w2t, sidx, nullptr, out);
}